// Round 15
// baseline (43158.685 us; speedup 1.0000x reference)
//
#include <hip/hip_runtime.h>

// NeuralCDE: B=64,T=256,C=16,S=64,H=128. fp32 recursion (f16 decorrelates).
// R12 6.52ms = single-CU stream floor (456KB/stage over ~134GB/s L2 port).
// R13: AGPRs work (128V+256A x 8 waves LAUNCHES => gfx950 = 512V + 512A per
// SIMD, two files!) but volatile AREADs trapped LDS loads -> 13.4ms.
// R14: cross-CU exchange = memory-side coherence, FETCH 207MB -> dead end.
// R15: single CU, THREE weight storage classes split BY WAVE PARITY:
//   even waves: W2 cols 0..63 in AGPRs (256/thread; 2 waves/SIMD = 512 = the
//     whole AGPR file; h2 preloaded to regs BEFORE volatile AREADs - R13 fix)
//   odd waves:  W2 cols 64..91 streamed (112KB/stage, only W2 L2 traffic)
//               + cols 92..127 from LDS [36][1024] (float4/thread, no bank
//               conflicts)
//   partials meet in sPA/sPB; P4 does tanh + k-reduce (R12 pattern).
// Per-stage L2: 96KB (W0/W1) + 112KB = 208KB (was 456). 4 barriers.

typedef float float4v __attribute__((ext_vector_type(4)));
typedef float float2v __attribute__((ext_vector_type(2)));

__device__ __forceinline__ float dot4(float4v a, float4v b) {
  return a.x * b.x + a.y * b.y + a.z * b.z + a.w * b.w;
}

__device__ __forceinline__ float softplus_fast(float x) {
  float z = __expf(-fabsf(x));
  return fmaxf(x, 0.f) + __logf(1.f + z);
}

__device__ __forceinline__ float tanh_hw(float x) {
  float e = __expf(2.f * x);  // inf-safe
  return 1.f - 2.f * __builtin_amdgcn_rcpf(e + 1.f);
}

#define AWRITE(dst, src) \
  asm volatile("v_accvgpr_write_b32 %0, %1" : "=a"(dst) : "v"(src))
#define AREADV(dst, src) \
  asm volatile("v_accvgpr_read_b32 %0, %1" : "=v"(dst) : "a"(src))

__global__ __launch_bounds__(512, 1) void cde_main(
    const float* __restrict__ xs,
    const float* __restrict__ icw0, const float* __restrict__ icb0,
    const float* __restrict__ icw1, const float* __restrict__ icb1,
    const float* __restrict__ icw2, const float* __restrict__ icb2,
    const float* __restrict__ vfw0, const float* __restrict__ vfb0,
    const float* __restrict__ vfw1, const float* __restrict__ vfb1,
    const float* __restrict__ vfw2, const float* __restrict__ vfb2,
    float* __restrict__ ybuf) {
  constexpr float Ac[6][5] = {
      {0.f, 0.f, 0.f, 0.f, 0.f},
      {0.161f, 0.f, 0.f, 0.f, 0.f},
      {-0.008480655492356989f, 0.335480655492357f, 0.f, 0.f, 0.f},
      {2.8971530571054935f, -6.359448489975075f, 4.3622954328695815f, 0.f, 0.f},
      {5.325864828439257f, -11.748883564062828f, 7.4955393428898365f,
       -0.09249506636175525f, 0.f},
      {5.86145544294642f, -12.92096931784711f, 8.159367898576159f,
       -0.071584973281401f, -0.028269050394068383f}};
  constexpr float SCv[6] = {0.f, 0.161f, 0.327f, 0.9f, 0.9800255409045097f, 1.f};
  constexpr float BWv[6] = {0.09646076681806523f, 0.01f, 0.4798896504144996f,
                            1.379008574103742f, -3.290069515436081f,
                            2.324710524099774f};

  const int tid = threadIdx.x;
  const int w = tid >> 6, l = tid & 63;
  const int b = blockIdx.x;  // one block per batch element
  const bool isA = (w & 1) == 0;          // even waves: AGPR class
  const int mloc = (w >> 1) * 64 + l;     // class-local 0..255
  const int rbase = 4 * mloc;             // owns W2 rows rbase..rbase+3

  __shared__ float sW2t[36][1024];             // W2 cols 92..127 col-major
  __shared__ __align__(16) float sYtw[8][64];  // wave-private stage inputs
  __shared__ __align__(16) float sH1[128];
  __shared__ __align__(16) float sH2[128];
  __shared__ __align__(16) float sPA[1024];    // class-A row partials
  __shared__ __align__(16) float sPB[1024];    // class-B row partials
  __shared__ float sK[6][64];

  // ---- one-time: LDS W2 tail cols 92..127 ----
  for (int i = tid; i < 36 * 1024; i += 512) {
    int k = i >> 10, r = i & 1023;
    sW2t[k][r] = vfw2[(size_t)r * 128 + 92 + k];
  }

  // ---- one-time: class-A AGPR residency (W2 rows rbase..+3, cols 0..63) --
  float w2ag[256];  // only ever indexed with constants; lives in AGPRs
  if (isA) {
#pragma unroll
    for (int rr = 0; rr < 4; ++rr) {
      const float4v* p = (const float4v*)(vfw2 + (size_t)(rbase + rr) * 128);
#pragma unroll
      for (int c4 = 0; c4 < 16; ++c4) {
        float4v v = p[c4];
        AWRITE(w2ag[rr * 64 + 4 * c4 + 0], v.x);
        AWRITE(w2ag[rr * 64 + 4 * c4 + 1], v.y);
        AWRITE(w2ag[rr * 64 + 4 * c4 + 2], v.z);
        AWRITE(w2ag[rr * 64 + 4 * c4 + 3], v.w);
      }
    }
  }

  // per-thread constants
  const int r0 = 2 * tid, r1 = r0 + 1;   // P4 rows
  const float b2r0 = vfb2[r0], b2r1 = vfb2[r1];
  const int c0 = r0 & 15;                // dx channels c0, c0+1 (P4)
  const int ii = tid >> 2, q4 = tid & 3; // h1/h2 roles
  const float b0i = vfb0[ii], b1i = vfb1[ii];

  const float* Xb = xs + (size_t)b * 4096;
  float* yb = ybuf + (size_t)b * 16384;

  __syncthreads();

  // ---- initial condition MLP (one-time; temps alias sPA) ----
  float* sTA = sPA;
  float* sTB = sPA + 128;
  if (tid < 128) {
    float a = icb0[tid];
    const float* wr = icw0 + tid * 16;
#pragma unroll
    for (int k = 0; k < 16; ++k) a += wr[k] * Xb[k];
    sTA[tid] = softplus_fast(a);
  }
  __syncthreads();
  if (tid < 128) {
    float a = icb1[tid];
    const float* wr = icw1 + tid * 128;
    for (int k = 0; k < 128; ++k) a += wr[k] * sTA[k];
    sTB[tid] = softplus_fast(a);
  }
  __syncthreads();
  if (tid < 64) {
    float a = icb2[tid];
    const float* wr = icw2 + tid * 128;
    for (int k = 0; k < 128; ++k) a += wr[k] * sTB[k];
    sH2[tid] = a;  // temp broadcast slot
  }
  __syncthreads();
  float yreg = sH2[l];  // every wave holds y[l]
  if (w == 0) yb[l] = yreg;
  __syncthreads();

  const float hstep = 1.f / 255.f;
  const float invh = 255.f;

#pragma unroll 1
  for (int t = 0; t < 255; ++t) {
    // per-lane dXdt basis for channels (c0, c0+1) — used in P4
    float2v xt = *(const float2v*)(Xb + t * 16 + c0);
    float2v xt1 = *(const float2v*)(Xb + (t + 1) * 16 + c0);
    float2v xtm = xt;
    if (t != 0) xtm = *(const float2v*)(Xb + (t - 1) * 16 + c0);
    const float u0 = xt.x - xt1.x, u1 = xt.y - xt1.y;
    const float dp0 = (xt1.x - xt.x) * invh;
    const float dp1 = (xt1.y - xt.y) * invh;
    const float di0 = (t == 0) ? dp0 : (xt.x - xtm.x) * invh;
    const float di1 = (t == 0) ? dp1 : (xt.y - xtm.y) * invh;
#pragma unroll 1
    for (int j = 0; j < 6; ++j) {
      // ---- P0: stage input y_j, per-wave private (in-wave wait only) ----
      {
        float yt = yreg;
#pragma unroll
        for (int m = 0; m < 5; ++m)
          if (m < j) yt += hstep * Ac[j][m] * sK[m][l];
        sYtw[w][l] = yt;
      }
      asm volatile("s_waitcnt lgkmcnt(0)" ::: "memory");
      const float sc = SCv[j], s2 = sc * sc;
      const float a1c = (6.f * s2 - 6.f * sc) * invh;
      const float a2c = 3.f * s2 - 4.f * sc + 1.f;
      const float a3c = 3.f * s2 - 2.f * sc;
      const float dx0 = a1c * u0 + a2c * di0 + a3c * dp0;
      const float dx1 = a1c * u1 + a2c * di1 + a3c * dp1;
      // ---- P1: h1 = softplus(W0 @ y + b0), W0 streamed ----
      {
        const float4v* w0p = (const float4v*)(vfw0 + (size_t)ii * 64 + q4 * 16);
        const float4v* yv = (const float4v*)(&sYtw[w][0] + q4 * 16);
        float s = dot4(w0p[0], yv[0]) + dot4(w0p[1], yv[1]) +
                  dot4(w0p[2], yv[2]) + dot4(w0p[3], yv[3]);
        s += __shfl_xor(s, 1);
        s += __shfl_xor(s, 2);
        if (q4 == 0) sH1[ii] = softplus_fast(s + b0i);
      }
      __syncthreads();  // barrier A
      // ---- class-B stream issue: W2 rows rbase..+3, cols 64..91 ----
      float4v stm[28];
      if (!isA) {
#pragma unroll
        for (int rr = 0; rr < 4; ++rr)
#pragma unroll
          for (int cc = 0; cc < 7; ++cc)
            stm[rr * 7 + cc] = *(const float4v*)(
                vfw2 + (size_t)(rbase + rr) * 128 + 64 + 4 * cc);
      }
      // ---- P2: h2 = softplus(W1 @ h1 + b1), W1 streamed ----
      {
        const float4v* w1p =
            (const float4v*)(vfw1 + (size_t)ii * 128 + q4 * 32);
        const float4v* hv = (const float4v*)(sH1 + q4 * 32);
        float s = 0.f;
#pragma unroll
        for (int kk = 0; kk < 8; ++kk) s += dot4(w1p[kk], hv[kk]);
        s += __shfl_xor(s, 1);
        s += __shfl_xor(s, 2);
        if (q4 == 0) sH2[ii] = softplus_fast(s + b1i);
      }
      __syncthreads();  // barrier B
      // ---- P3: row-partial dots, class-split by wave parity ----
      if (isA) {
        // preload h2[0..63] BEFORE volatile AREADs (R13 lesson)
        float4v h2p[16];
#pragma unroll
        for (int c4 = 0; c4 < 16; ++c4) h2p[c4] = ((const float4v*)sH2)[c4];
        asm volatile("s_waitcnt lgkmcnt(0)" ::: "memory");
        float a0 = 0.f, a1 = 0.f, a2 = 0.f, a3 = 0.f;
#pragma unroll
        for (int c4 = 0; c4 < 16; ++c4) {
          float4v h = h2p[c4];
#pragma unroll
          for (int cc = 0; cc < 4; ++cc) {
            float hc = cc == 0 ? h.x : cc == 1 ? h.y : cc == 2 ? h.z : h.w;
            float t0, t1, t2, t3;
            AREADV(t0, w2ag[0 * 64 + 4 * c4 + cc]);
            AREADV(t1, w2ag[1 * 64 + 4 * c4 + cc]);
            AREADV(t2, w2ag[2 * 64 + 4 * c4 + cc]);
            AREADV(t3, w2ag[3 * 64 + 4 * c4 + cc]);
            a0 += t0 * hc;
            a1 += t1 * hc;
            a2 += t2 * hc;
            a3 += t3 * hc;
          }
        }
        float4v acc = {a0, a1, a2, a3};
        *(float4v*)&sPA[rbase] = acc;
      } else {
        float4v h2p[16];  // h2[64..127]
#pragma unroll
        for (int c4 = 0; c4 < 16; ++c4)
          h2p[c4] = ((const float4v*)(sH2 + 64))[c4];
        float a0 = 0.f, a1 = 0.f, a2 = 0.f, a3 = 0.f;
        // streamed cols 64..91
#pragma unroll
        for (int cc = 0; cc < 7; ++cc) {
          float4v h = h2p[cc];
          float4v wv0 = stm[0 * 7 + cc], wv1 = stm[1 * 7 + cc];
          float4v wv2 = stm[2 * 7 + cc], wv3 = stm[3 * 7 + cc];
          a0 += dot4(wv0, h);
          a1 += dot4(wv1, h);
          a2 += dot4(wv2, h);
          a3 += dot4(wv3, h);
        }
        // LDS cols 92..127
#pragma unroll
        for (int k = 0; k < 36; ++k) {
          float4v wv = *(const float4v*)&sW2t[k][rbase];
          int si = 28 + k;  // h2 slice index
          float4v hs = h2p[si >> 2];
          float hc = (si & 3) == 0   ? hs.x
                     : (si & 3) == 1 ? hs.y
                     : (si & 3) == 2 ? hs.z
                                     : hs.w;
          a0 += wv.x * hc;
          a1 += wv.y * hc;
          a2 += wv.z * hc;
          a3 += wv.w * hc;
        }
        float4v acc = {a0, a1, a2, a3};
        *(float4v*)&sPB[rbase] = acc;
      }
      __syncthreads();  // barrier C
      // ---- P4: tanh + k-reduce over channels (R12 pattern) ----
      {
        float aa = sPA[r0] + sPB[r0] + b2r0;
        float ab = sPA[r1] + sPB[r1] + b2r1;
        float f = tanh_hw(aa) * dx0 + tanh_hw(ab) * dx1;
        f += __shfl_xor(f, 1);
        f += __shfl_xor(f, 2);
        f += __shfl_xor(f, 4);
        if ((tid & 7) == 0) sK[j][tid >> 3] = f;
      }
      __syncthreads();  // barrier D
    }
    // ---- y_{t+1}: every wave redundantly; wave0 dumps the state ----
    {
      float yn = yreg;
#pragma unroll
      for (int m = 0; m < 6; ++m) yn += hstep * BWv[m] * sK[m][l];
      yreg = yn;
      if (w == 0) yb[(size_t)(t + 1) * 64 + l] = yn;
    }
  }
}

// Parallel readout: one thread per (b,t): out6 = y @ ro^T + rob, 6D->SO(3).
__global__ __launch_bounds__(256) void readout(
    const float* __restrict__ ybuf, const float* __restrict__ row,
    const float* __restrict__ rob, float* __restrict__ out) {
  int idx = blockIdx.x * blockDim.x + threadIdx.x;  // b*256+t
  const float* y = ybuf + (size_t)idx * 64;
  float p[6];
#pragma unroll
  for (int o = 0; o < 6; ++o) {
    const float4v* rr = (const float4v*)(row + o * 64);
    const float4v* yv = (const float4v*)y;
    float s = 0.f;
#pragma unroll
    for (int k = 0; k < 16; ++k) s += dot4(rr[k], yv[k]);
    p[o] = s + rob[o];
  }
  float a1x = p[0], a1y = p[1], a1z = p[2];
  float a2x = p[3], a2y = p[4], a2z = p[5];
  float n1 = rsqrtf(a1x * a1x + a1y * a1y + a1z * a1z);
  float b1x = a1x * n1, b1y = a1y * n1, b1z = a1z * n1;
  float d = b1x * a2x + b1y * a2y + b1z * a2z;
  float px = a2x - d * b1x, py = a2y - d * b1y, pz = a2z - d * b1z;
  float n2 = rsqrtf(px * px + py * py + pz * pz);
  float b2x = px * n2, b2y = py * n2, b2z = pz * n2;
  float b3x = b1y * b2z - b1z * b2y;
  float b3y = b1z * b2x - b1x * b2z;
  float b3z = b1x * b2y - b1y * b2x;
  float* o = out + (size_t)idx * 9;
  o[0] = b1x; o[1] = b2x; o[2] = b3x;
  o[3] = b1y; o[4] = b2y; o[5] = b3y;
  o[6] = b1z; o[7] = b2z; o[8] = b3z;
}

extern "C" void kernel_launch(void* const* d_in, const int* in_sizes, int n_in,
                              void* d_out, int out_size, void* d_ws,
                              size_t ws_size, hipStream_t stream) {
  (void)in_sizes; (void)n_in; (void)out_size; (void)ws_size;
  const float* xs   = (const float*)d_in[0];
  const float* icw0 = (const float*)d_in[1];
  const float* icb0 = (const float*)d_in[2];
  const float* icw1 = (const float*)d_in[3];
  const float* icb1 = (const float*)d_in[4];
  const float* icw2 = (const float*)d_in[5];
  const float* icb2 = (const float*)d_in[6];
  const float* vfw0 = (const float*)d_in[7];
  const float* vfb0 = (const float*)d_in[8];
  const float* vfw1 = (const float*)d_in[9];
  const float* vfb1 = (const float*)d_in[10];
  const float* vfw2 = (const float*)d_in[11];
  const float* vfb2 = (const float*)d_in[12];
  const float* row  = (const float*)d_in[13];
  const float* rob  = (const float*)d_in[14];
  float* ybuf = (float*)d_ws;  // 64*256*64 floats = 4 MB

  hipLaunchKernelGGL(cde_main, dim3(64), dim3(512), 0, stream,
                     xs, icw0, icb0, icw1, icb1, icw2, icb2,
                     vfw0, vfb0, vfw1, vfb1, vfw2, vfb2, ybuf);
  hipLaunchKernelGGL(readout, dim3(64), dim3(256), 0, stream,
                     ybuf, row, rob, (float*)d_out);
}

// Round 17
// 34594.135 us; speedup vs baseline: 1.2476x; 1.2476x over previous
//
#include <hip/hip_runtime.h>

// NeuralCDE: B=64,T=256,C=16,S=64,H=128. fp32 recursion (f16 decorrelates).
// Facts bank: R12 6.52ms = 1-CU stream floor (456KB/stage over ~134GB/s L2
// port). R13: 256 AGPR/thread launches & works (gfx950: 512 VGPR + 512 AGPR
// per SIMD; AGPR file alone = 512KB/CU = exactly W2). R14 cross-CU sync =
// memory-side coherence, dead. R15 split-class = 2x volatile walls, 43ms.
// R16: clean AGPR k-phase but WRONG REDUCTION (f missing shfl_xor 1,2 ->
// k[s] summed only channels {0,1,8,9}) -> absmax 1.996.
// R17 = R16 + the two missing shuffles. Isolated fix to measure the AGPR
// k-phase timing honestly.
//  - thread (g=tid>>2,q=tid&3) owns W2 rows 8g..8g+7 x cols 32q..32q+31
//    in 256 AGPRs (2 waves/SIMD x 256 = whole AGPR file).
//  - k-phase: preload own h2 quarter (8 ds_read_b128) -> lgkm wait -> 256
//    AREAD+FMA, 8 indep accumulators, zero LDS inside the volatile region ->
//    quad-reduce acc (xor 1,2) -> tanh*dx -> f-reduce over xor 1,2,4 -> sK.
//  - W0/W1 streamed from L2 at stage top (96KB/stage, hidden under P0/h1).
//  - 3 barriers/stage; dXdt in regs (R11); y->d_ws + parallel readout (R10).

typedef float float4v __attribute__((ext_vector_type(4)));
typedef float float2v __attribute__((ext_vector_type(2)));

__device__ __forceinline__ float dot4(float4v a, float4v b) {
  return a.x * b.x + a.y * b.y + a.z * b.z + a.w * b.w;
}

__device__ __forceinline__ float softplus_fast(float x) {
  float z = __expf(-fabsf(x));
  return fmaxf(x, 0.f) + __logf(1.f + z);
}

__device__ __forceinline__ float tanh_hw(float x) {
  float e = __expf(2.f * x);  // inf-safe
  return 1.f - 2.f * __builtin_amdgcn_rcpf(e + 1.f);
}

#define AWRITE(dst, src) \
  asm volatile("v_accvgpr_write_b32 %0, %1" : "=a"(dst) : "v"(src))
#define AREADV(dst, src) \
  asm volatile("v_accvgpr_read_b32 %0, %1" : "=v"(dst) : "a"(src))

__global__ __launch_bounds__(512, 1) void cde_main(
    const float* __restrict__ xs,
    const float* __restrict__ icw0, const float* __restrict__ icb0,
    const float* __restrict__ icw1, const float* __restrict__ icb1,
    const float* __restrict__ icw2, const float* __restrict__ icb2,
    const float* __restrict__ vfw0, const float* __restrict__ vfb0,
    const float* __restrict__ vfw1, const float* __restrict__ vfb1,
    const float* __restrict__ vfw2, const float* __restrict__ vfb2,
    float* __restrict__ ybuf) {
  constexpr float Ac[6][5] = {
      {0.f, 0.f, 0.f, 0.f, 0.f},
      {0.161f, 0.f, 0.f, 0.f, 0.f},
      {-0.008480655492356989f, 0.335480655492357f, 0.f, 0.f, 0.f},
      {2.8971530571054935f, -6.359448489975075f, 4.3622954328695815f, 0.f, 0.f},
      {5.325864828439257f, -11.748883564062828f, 7.4955393428898365f,
       -0.09249506636175525f, 0.f},
      {5.86145544294642f, -12.92096931784711f, 8.159367898576159f,
       -0.071584973281401f, -0.028269050394068383f}};
  constexpr float SCv[6] = {0.f, 0.161f, 0.327f, 0.9f, 0.9800255409045097f, 1.f};
  constexpr float BWv[6] = {0.09646076681806523f, 0.01f, 0.4798896504144996f,
                            1.379008574103742f, -3.290069515436081f,
                            2.324710524099774f};

  const int tid = threadIdx.x;
  const int w = tid >> 6, l = tid & 63;
  const int b = blockIdx.x;             // one block per batch element
  const int g = tid >> 2, q = tid & 3;  // row-group / col-quarter (and h role)

  __shared__ __align__(16) float sYtw[8][64];  // wave-private stage inputs
  __shared__ __align__(16) float sH1[128];
  __shared__ __align__(16) float sH2[128];
  __shared__ __align__(16) float sY0[64];
  __shared__ float sK[6][64];

  // ---- one-time: W2 rows 8g..8g+7, cols 32q..32q+31 -> 256 AGPRs ----
  float w2ag[256];  // constant-indexed only; lives in AGPR file
#pragma unroll
  for (int p = 0; p < 8; ++p) {
    const float4v* src =
        (const float4v*)(vfw2 + (size_t)(8 * g + p) * 128 + 32 * q);
#pragma unroll
    for (int c4 = 0; c4 < 8; ++c4) {
      float4v v = src[c4];
      AWRITE(w2ag[p * 32 + 4 * c4 + 0], v.x);
      AWRITE(w2ag[p * 32 + 4 * c4 + 1], v.y);
      AWRITE(w2ag[p * 32 + 4 * c4 + 2], v.z);
      AWRITE(w2ag[p * 32 + 4 * c4 + 3], v.w);
    }
  }

  // per-thread constants
  const int ra = 8 * g + 2 * q, rb = ra + 1;  // rows this lane tanh-handles
  const float b2a = vfb2[ra], b2b = vfb2[rb];
  const int c0 = ra & 15;                     // dx channels c0, c0+1
  const float b0i = vfb0[g], b1i = vfb1[g];
  const float4v* w0p = (const float4v*)(vfw0 + (size_t)g * 64 + q * 16);
  const float4v* w1p = (const float4v*)(vfw1 + (size_t)g * 128 + q * 32);

  const float* Xb = xs + (size_t)b * 4096;
  float* yb = ybuf + (size_t)b * 16384;

  __syncthreads();

  // ---- initial condition MLP (one-time; temps in sH1/sH2) ----
  if (tid < 128) {
    float a = icb0[tid];
    const float* wr = icw0 + tid * 16;
#pragma unroll
    for (int k = 0; k < 16; ++k) a += wr[k] * Xb[k];
    sH1[tid] = softplus_fast(a);
  }
  __syncthreads();
  if (tid < 128) {
    float a = icb1[tid];
    const float* wr = icw1 + tid * 128;
    for (int k = 0; k < 128; ++k) a += wr[k] * sH1[k];
    sH2[tid] = softplus_fast(a);
  }
  __syncthreads();
  if (tid < 64) {
    float a = icb2[tid];
    const float* wr = icw2 + tid * 128;
    for (int k = 0; k < 128; ++k) a += wr[k] * sH2[k];
    sY0[tid] = a;
  }
  __syncthreads();
  float yreg = sY0[l];  // every wave holds y[l]
  if (w == 0) yb[l] = yreg;
  __syncthreads();  // sH1/sH2 temps done before stage use

  const float hstep = 1.f / 255.f;
  const float invh = 255.f;

#pragma unroll 1
  for (int t = 0; t < 255; ++t) {
    // per-lane dXdt basis for channels (c0, c0+1)
    float2v xt = *(const float2v*)(Xb + t * 16 + c0);
    float2v xt1 = *(const float2v*)(Xb + (t + 1) * 16 + c0);
    float2v xtm = xt;
    if (t != 0) xtm = *(const float2v*)(Xb + (t - 1) * 16 + c0);
    const float u0 = xt.x - xt1.x, u1 = xt.y - xt1.y;
    const float dp0 = (xt1.x - xt.x) * invh;
    const float dp1 = (xt1.y - xt.y) * invh;
    const float di0 = (t == 0) ? dp0 : (xt.x - xtm.x) * invh;
    const float di1 = (t == 0) ? dp1 : (xt.y - xtm.y) * invh;
#pragma unroll 1
    for (int j = 0; j < 6; ++j) {
      // ---- early stream issue: W0/W1 slices (consumed in h1/h2) ----
      float4v w0r[4];
#pragma unroll
      for (int kk = 0; kk < 4; ++kk) w0r[kk] = w0p[kk];
      float4v w1r[8];
#pragma unroll
      for (int kk = 0; kk < 8; ++kk) w1r[kk] = w1p[kk];
      // ---- P0: stage input y_j, per-wave private (in-wave wait only) ----
      {
        float yt = yreg;
#pragma unroll
        for (int m = 0; m < 5; ++m)
          if (m < j) yt += hstep * Ac[j][m] * sK[m][l];
        sYtw[w][l] = yt;
      }
      asm volatile("s_waitcnt lgkmcnt(0)" ::: "memory");
      const float sc = SCv[j], s2 = sc * sc;
      const float a1c = (6.f * s2 - 6.f * sc) * invh;
      const float a2c = 3.f * s2 - 4.f * sc + 1.f;
      const float a3c = 3.f * s2 - 2.f * sc;
      const float dx0 = a1c * u0 + a2c * di0 + a3c * dp0;
      const float dx1 = a1c * u1 + a2c * di1 + a3c * dp1;
      // ---- h1 = softplus(W0 @ y + b0), W0 streamed ----
      {
        const float4v* yv = (const float4v*)(&sYtw[w][0] + q * 16);
        float s = dot4(w0r[0], yv[0]) + dot4(w0r[1], yv[1]) +
                  dot4(w0r[2], yv[2]) + dot4(w0r[3], yv[3]);
        s += __shfl_xor(s, 1);
        s += __shfl_xor(s, 2);
        if (q == 0) sH1[g] = softplus_fast(s + b0i);
      }
      __syncthreads();  // A
      // ---- h2 = softplus(W1 @ h1 + b1), W1 streamed ----
      {
        const float4v* hv = (const float4v*)(sH1 + q * 32);
        float s = 0.f;
#pragma unroll
        for (int kk = 0; kk < 8; ++kk) s += dot4(w1r[kk], hv[kk]);
        s += __shfl_xor(s, 1);
        s += __shfl_xor(s, 2);
        if (q == 0) sH2[g] = softplus_fast(s + b1i);
      }
      __syncthreads();  // B
      // ---- k-phase: rows 8g..8g+7 x cols 32q..+31 from AGPRs ----
      {
        // preload own h2 quarter BEFORE any volatile asm
        float4v h2p[8];
        const float4v* hq = (const float4v*)(sH2 + 32 * q);
#pragma unroll
        for (int c4 = 0; c4 < 8; ++c4) h2p[c4] = hq[c4];
        asm volatile("s_waitcnt lgkmcnt(0)" ::: "memory");
        float acc[8] = {0.f, 0.f, 0.f, 0.f, 0.f, 0.f, 0.f, 0.f};
#pragma unroll
        for (int c4 = 0; c4 < 8; ++c4) {
          float4v h = h2p[c4];
#pragma unroll
          for (int p = 0; p < 8; ++p) {
            float t0, t1, t2, t3;
            AREADV(t0, w2ag[p * 32 + 4 * c4 + 0]);
            AREADV(t1, w2ag[p * 32 + 4 * c4 + 1]);
            AREADV(t2, w2ag[p * 32 + 4 * c4 + 2]);
            AREADV(t3, w2ag[p * 32 + 4 * c4 + 3]);
            acc[p] += t0 * h.x + t1 * h.y + t2 * h.z + t3 * h.w;
          }
        }
        // quad reduction: sum col-quarters (lanes differing in bits 0,1)
#pragma unroll
        for (int p = 0; p < 8; ++p) {
          acc[p] += __shfl_xor(acc[p], 1);
          acc[p] += __shfl_xor(acc[p], 2);
        }
        // lane handles rows ra=8g+2q, rb=ra+1
        float f = tanh_hw(acc[2 * q] + b2a) * dx0 +
                  tanh_hw(acc[2 * q + 1] + b2b) * dx1;
        // R16 BUG FIX: f must be reduced over bits 0,1 (the q contributions)
        // AND bit 2 (the row-group pair) — 8 lanes x 2 rows = 16 channels.
        f += __shfl_xor(f, 1);
        f += __shfl_xor(f, 2);
        f += __shfl_xor(f, 4);
        if ((tid & 7) == 0) sK[j][tid >> 3] = f;
      }
      __syncthreads();  // C
    }
    // ---- y_{t+1}: every wave redundantly; wave0 dumps the state ----
    {
      float yn = yreg;
#pragma unroll
      for (int m = 0; m < 6; ++m) yn += hstep * BWv[m] * sK[m][l];
      yreg = yn;
      if (w == 0) yb[(size_t)(t + 1) * 64 + l] = yn;
    }
  }
}

// Parallel readout: one thread per (b,t): out6 = y @ ro^T + rob, 6D->SO(3).
__global__ __launch_bounds__(256) void readout(
    const float* __restrict__ ybuf, const float* __restrict__ row,
    const float* __restrict__ rob, float* __restrict__ out) {
  int idx = blockIdx.x * blockDim.x + threadIdx.x;  // b*256+t
  const float* y = ybuf + (size_t)idx * 64;
  float p[6];
#pragma unroll
  for (int o = 0; o < 6; ++o) {
    const float4v* rr = (const float4v*)(row + o * 64);
    const float4v* yv = (const float4v*)y;
    float s = 0.f;
#pragma unroll
    for (int k = 0; k < 16; ++k) s += dot4(rr[k], yv[k]);
    p[o] = s + rob[o];
  }
  float a1x = p[0], a1y = p[1], a1z = p[2];
  float a2x = p[3], a2y = p[4], a2z = p[5];
  float n1 = rsqrtf(a1x * a1x + a1y * a1y + a1z * a1z);
  float b1x = a1x * n1, b1y = a1y * n1, b1z = a1z * n1;
  float d = b1x * a2x + b1y * a2y + b1z * a2z;
  float px = a2x - d * b1x, py = a2y - d * b1y, pz = a2z - d * b1z;
  float n2 = rsqrtf(px * px + py * py + pz * pz);
  float b2x = px * n2, b2y = py * n2, b2z = pz * n2;
  float b3x = b1y * b2z - b1z * b2y;
  float b3y = b1z * b2x - b1x * b2z;
  float b3z = b1x * b2y - b1y * b2x;
  float* o = out + (size_t)idx * 9;
  o[0] = b1x; o[1] = b2x; o[2] = b3x;
  o[3] = b1y; o[4] = b2y; o[5] = b3y;
  o[6] = b1z; o[7] = b2z; o[8] = b3z;
}

extern "C" void kernel_launch(void* const* d_in, const int* in_sizes, int n_in,
                              void* d_out, int out_size, void* d_ws,
                              size_t ws_size, hipStream_t stream) {
  (void)in_sizes; (void)n_in; (void)out_size; (void)ws_size;
  const float* xs   = (const float*)d_in[0];
  const float* icw0 = (const float*)d_in[1];
  const float* icb0 = (const float*)d_in[2];
  const float* icw1 = (const float*)d_in[3];
  const float* icb1 = (const float*)d_in[4];
  const float* icw2 = (const float*)d_in[5];
  const float* icb2 = (const float*)d_in[6];
  const float* vfw0 = (const float*)d_in[7];
  const float* vfb0 = (const float*)d_in[8];
  const float* vfw1 = (const float*)d_in[9];
  const float* vfb1 = (const float*)d_in[10];
  const float* vfw2 = (const float*)d_in[11];
  const float* vfb2 = (const float*)d_in[12];
  const float* row  = (const float*)d_in[13];
  const float* rob  = (const float*)d_in[14];
  float* ybuf = (float*)d_ws;  // 64*256*64 floats = 4 MB

  hipLaunchKernelGGL(cde_main, dim3(64), dim3(512), 0, stream,
                     xs, icw0, icb0, icw1, icb1, icw2, icb2,
                     vfw0, vfb0, vfw1, vfb1, vfw2, vfb2, ybuf);
  hipLaunchKernelGGL(readout, dim3(64), dim3(256), 0, stream,
                     ybuf, row, rob, (float*)d_out);
}